// Round 1
// baseline (248.220 us; speedup 1.0000x reference)
//
#include <hip/hip_runtime.h>

// Pool255: out = (1/8) * sum over 8 directional cumulative-max pools.
// x: [8,256,128,128] fp32. One block per (b,c) image.
//
// 4 line families, each covering 2 opposite directions:
//   V: columns      -> dirs (1,0) suffix, (-1,0) prefix
//   H: rows         -> dirs (0,1) suffix, (0,-1) prefix
//   D: diagonals    -> dirs (1,1) suffix, (-1,-1) prefix  (walk +1,+1)
//   A: anti-diags   -> dirs (1,-1) suffix, (-1,1) prefix  (walk +1,-1)
// One thread per line; forward pass adds prefix-max, backward pass adds
// suffix-max into acc. Barriers between families. acc *= 1/8 at store.

#define HH 128
#define WW 128
#define STRIDE 129          // odd stride: conflict-free col access, 2-way (free) row access
#define NPIX (HH * WW)

__global__ __launch_bounds__(256) void pool255_kernel(const float* __restrict__ x,
                                                      float* __restrict__ out) {
    __shared__ float tile[HH * STRIDE];
    __shared__ float acc[HH * STRIDE];

    const int img = blockIdx.x;
    const float* __restrict__ xim = x + (size_t)img * NPIX;
    float* __restrict__ oim = out + (size_t)img * NPIX;
    const int t = threadIdx.x;
    const float NEG = -3.402823466e38f;

    // ---- load: 4096 float4 / 256 threads = 16 each, coalesced ----
    const float4* __restrict__ xv = (const float4*)xim;
    #pragma unroll
    for (int r = 0; r < 16; ++r) {
        int idx4 = t + r * 256;          // float4 index
        float4 v = xv[idx4];
        int p = idx4 << 2;
        int i = p >> 7, j = p & 127;
        float* dst = &tile[i * STRIDE + j];
        dst[0] = v.x; dst[1] = v.y; dst[2] = v.z; dst[3] = v.w;
    }
    __syncthreads();

    // ---- V family: one thread per column ----
    if (t < 128) {
        float run = NEG;
        int o = t;
        #pragma unroll 4
        for (int i = 0; i < HH; ++i) { run = fmaxf(run, tile[o]); acc[o] = run; o += STRIDE; }
        run = NEG;
        o = (HH - 1) * STRIDE + t;
        #pragma unroll 4
        for (int i = 0; i < HH; ++i) { run = fmaxf(run, tile[o]); acc[o] += run; o -= STRIDE; }
    }
    __syncthreads();

    // ---- H family: one thread per row ----
    if (t < 128) {
        float run = NEG;
        int o = t * STRIDE;
        #pragma unroll 4
        for (int j = 0; j < WW; ++j) { run = fmaxf(run, tile[o]); acc[o] += run; ++o; }
        run = NEG;
        o = t * STRIDE + (WW - 1);
        #pragma unroll 4
        for (int j = 0; j < WW; ++j) { run = fmaxf(run, tile[o]); acc[o] += run; --o; }
    }
    __syncthreads();

    // ---- D family: diagonals j - i = t - 127, walk (+1,+1) ----
    if (t < 255) {
        int od = t - 127;
        int i0 = od >= 0 ? 0 : -od;
        int j0 = od >= 0 ? od : 0;
        int len = 128 - (od >= 0 ? od : -od);
        float run = NEG;
        int o = i0 * STRIDE + j0;
        #pragma unroll 4
        for (int k = 0; k < len; ++k) { run = fmaxf(run, tile[o]); acc[o] += run; o += STRIDE + 1; }
        run = NEG;
        o = (i0 + len - 1) * STRIDE + (j0 + len - 1);
        #pragma unroll 4
        for (int k = 0; k < len; ++k) { run = fmaxf(run, tile[o]); acc[o] += run; o -= STRIDE + 1; }
    }
    __syncthreads();

    // ---- A family: anti-diagonals i + j = t, walk (+1,-1) ----
    if (t < 255) {
        int s = t;
        int i0 = (s < 128) ? 0 : (s - 127);
        int j0 = s - i0;
        int len = (s < 128) ? (s + 1) : (255 - s);
        float run = NEG;
        int o = i0 * STRIDE + j0;
        #pragma unroll 4
        for (int k = 0; k < len; ++k) { run = fmaxf(run, tile[o]); acc[o] += run; o += STRIDE - 1; }
        run = NEG;
        o = (i0 + len - 1) * STRIDE + (j0 - (len - 1));
        #pragma unroll 4
        for (int k = 0; k < len; ++k) { run = fmaxf(run, tile[o]); acc[o] += run; o -= STRIDE - 1; }
    }
    __syncthreads();

    // ---- store: out = acc * 1/8, coalesced float4 ----
    float4* __restrict__ ov = (float4*)oim;
    #pragma unroll
    for (int r = 0; r < 16; ++r) {
        int idx4 = t + r * 256;
        int p = idx4 << 2;
        int i = p >> 7, j = p & 127;
        const float* src = &acc[i * STRIDE + j];
        float4 v;
        v.x = src[0] * 0.125f;
        v.y = src[1] * 0.125f;
        v.z = src[2] * 0.125f;
        v.w = src[3] * 0.125f;
        ov[idx4] = v;
    }
}

extern "C" void kernel_launch(void* const* d_in, const int* in_sizes, int n_in,
                              void* d_out, int out_size, void* d_ws, size_t ws_size,
                              hipStream_t stream) {
    const float* x = (const float*)d_in[0];
    float* out = (float*)d_out;
    int n_img = in_sizes[0] / NPIX;   // 8*256 = 2048
    pool255_kernel<<<n_img, 256, 0, stream>>>(x, out);
}

// Round 2
// 175.047 us; speedup vs baseline: 1.4180x; 1.4180x over previous
//
#include <hip/hip_runtime.h>

// Pool255: out = (1/8) * sum of 8 directional cumulative-max pools.
// x: [8,256,128,128] fp32. One block (128 threads = 2 waves) per image.
//
// All 8 directions are 1-step row recurrences:
//   top-down  (wave0): (-1,0) vert, (-1,-1) pull j-1, (-1,+1) pull j+1, (0,-1) row prefix
//   bottom-up (wave1): (+1,0) vert, (+1,-1) pull j-1, (+1,+1) pull j+1, (0,+1) row suffix
// Lane l owns columns l (slot0) and l+64 (slot1) -> all column shifts stay
// inside one wave64 (shfl + boundary fixups), no per-row barriers.
// Phase 1 (64 rows): each wave writes its 4-dir partial (fp16) to LDS; the
// two waves cover disjoint row halves. One __syncthreads(). Phase 2: each
// wave combines with the other wave's partial and stores out directly.

#define NPIX 16384
#define NEGF (-3.402823466e38f)

template <int PHASE>
__device__ __forceinline__ void sweep_rows(
    const float* __restrict__ xim, float* __restrict__ oim, _Float16* part,
    int l, bool rev,
    float& v0, float& v1, float& d0, float& d1, float& a0, float& a1) {
  const int t0 = PHASE ? 64 : 0;
  const int t1 = PHASE ? 128 : 64;
  #pragma unroll 4
  for (int t = t0; t < t1; ++t) {
    const int row = rev ? 127 - t : t;
    const float* __restrict__ xr = xim + (row << 7);
    const float x0 = xr[l];
    const float x1 = xr[l + 64];

    // vertical running max
    v0 = fmaxf(v0, x0);
    v1 = fmaxf(v1, x1);

    // diagonal pulling from col-1 (shift right)
    {
      const float b = __shfl(d0, 63);           // prev-row col 63 -> new col 64
      float r0 = __shfl_up(d0, 1);
      float r1 = __shfl_up(d1, 1);
      if (l == 0) { r0 = NEGF; r1 = b; }
      d0 = fmaxf(x0, r0);
      d1 = fmaxf(x1, r1);
    }
    // diagonal pulling from col+1 (shift left)
    {
      const float b = __shfl(a1, 0);            // prev-row col 64 -> new col 63
      float u0 = __shfl_down(a0, 1);
      float u1 = __shfl_down(a1, 1);
      if (l == 63) { u0 = b; u1 = NEGF; }
      a0 = fmaxf(x0, u0);
      a1 = fmaxf(x1, u1);
    }

    // row scan: prefix (wave0) or suffix (wave1) over 128 cols
    float s0 = x0, s1 = x1;
    if (!rev) {
      #pragma unroll
      for (int off = 1; off < 64; off <<= 1) {
        const float t0v = __shfl_up(s0, off);
        const float t1v = __shfl_up(s1, off);
        if (l >= off) { s0 = fmaxf(s0, t0v); s1 = fmaxf(s1, t1v); }
      }
      s1 = fmaxf(s1, __shfl(s0, 63));           // slot1 prefix includes all of slot0
    } else {
      #pragma unroll
      for (int off = 1; off < 64; off <<= 1) {
        const float t0v = __shfl_down(s0, off);
        const float t1v = __shfl_down(s1, off);
        if (l < 64 - off) { s0 = fmaxf(s0, t0v); s1 = fmaxf(s1, t1v); }
      }
      s0 = fmaxf(s0, __shfl(s1, 0));            // slot0 suffix includes all of slot1
    }

    const float p0 = (v0 + d0) + (a0 + s0);
    const float p1 = (v1 + d1) + (a1 + s1);
    const int base = row << 7;
    if (PHASE == 0) {
      part[base + l]      = (_Float16)p0;
      part[base + 64 + l] = (_Float16)p1;
    } else {
      const float q0 = (float)part[base + l];
      const float q1 = (float)part[base + 64 + l];
      oim[base + l]      = (p0 + q0) * 0.125f;
      oim[base + 64 + l] = (p1 + q1) * 0.125f;
    }
  }
}

__global__ __launch_bounds__(128) void pool255_sweep(const float* __restrict__ x,
                                                     float* __restrict__ out) {
  __shared__ _Float16 part[NPIX];               // 32 KB -> 5 blocks/CU
  const int img = blockIdx.x;
  const float* __restrict__ xim = x + (size_t)img * NPIX;
  float* __restrict__ oim = out + (size_t)img * NPIX;
  const int l = threadIdx.x & 63;
  const bool rev = threadIdx.x >= 64;           // wave0: top-down, wave1: bottom-up

  float v0 = NEGF, v1 = NEGF, d0 = NEGF, d1 = NEGF, a0 = NEGF, a1 = NEGF;

  sweep_rows<0>(xim, oim, part, l, rev, v0, v1, d0, d1, a0, a1);
  __syncthreads();
  sweep_rows<1>(xim, oim, part, l, rev, v0, v1, d0, d1, a0, a1);
}

extern "C" void kernel_launch(void* const* d_in, const int* in_sizes, int n_in,
                              void* d_out, int out_size, void* d_ws, size_t ws_size,
                              hipStream_t stream) {
  const float* x = (const float*)d_in[0];
  float* out = (float*)d_out;
  const int n_img = in_sizes[0] / NPIX;         // 8*256 = 2048
  pool255_sweep<<<n_img, 128, 0, stream>>>(x, out);
}

// Round 4
// 88.703 us; speedup vs baseline: 2.7983x; 1.9734x over previous
//
#include <hip/hip_runtime.h>

// Pool255: out = (1/8) * sum of 8 directional cumulative-max pools.
// x: [8,256,128,128] fp32. One block (2 waves) per image.
//
// All 8 directions are 1-step row recurrences. Wave0 sweeps rows top-down
// computing dirs {(-1,0),(-1,-1),(-1,+1),(0,-1)}; wave1 sweeps bottom-up in a
// COLUMN-MIRRORED view (lane l <-> col 127-2l), which turns its 4 dirs
// {(1,0),(1,1),(1,-1),(0,1)} into the SAME recurrences -> identical code.
//
// Lane l owns 2 adjacent (view-)columns {2l, 2l+1}:
//  - vertical: register running max (no cross-lane)
//  - diag/anti: ONE ds_bpermute (shift by 1 lane) each; other slot is local
//  - row prefix-max: 6-step DPP scan (row_shr 1/2/4/8 + row_bcast15/31),
//    pure VALU, + one bpermute for the exclusive value
// Per row-wave: 3 bpermute + 1 LDS part op (vs 21 LDS ops in R2).
// Phase 1 writes 4-dir partial as packed fp16x2 to LDS; one barrier; phase 2
// combines with the other wave's partial and stores out.

#define NPIX 16384
#define NEGF (-3.402823466e38f)

typedef __fp16 half2v __attribute__((ext_vector_type(2)));

// y = max(y, dpp_move(y)) ; invalid/masked lanes keep old=y (no-op)
#define DPP_MAXSTEP(y, ctrl, rmask)                                          \
  y = fmaxf(y, __int_as_float(__builtin_amdgcn_update_dpp(                   \
                 __float_as_int(y), __float_as_int(y), ctrl, rmask, 0xf,     \
                 false)))

template <bool MIR, int PHASE>
__device__ __forceinline__ void sweep(const float* __restrict__ xim,
                                      float* __restrict__ oim,
                                      unsigned* __restrict__ part, int l,
                                      int addr_m1, int addr_p1, float& v0,
                                      float& v1, float& d0, float& d1,
                                      float& a0, float& a1) {
  const int t0 = PHASE ? 64 : 0, t1 = PHASE ? 128 : 64;
  const int off = MIR ? (63 - l) * 2 : l * 2;  // float index of the col pair
  const int slot = MIR ? (63 - l) : l;         // u32 slot in part row
#pragma unroll 2
  for (int t = t0; t < t1; ++t) {
    const int row = MIR ? (127 - t) : t;       // real row
    const float2 xv = *(const float2*)(xim + (row << 7) + off);
    const float x0 = MIR ? xv.y : xv.x;        // view col 2l
    const float x1 = MIR ? xv.x : xv.y;        // view col 2l+1

    // vertical
    v0 = fmaxf(v0, x0);
    v1 = fmaxf(v1, x1);

    // diagonal: D[c] = max(x[c], Dprev[c-1])
    {
      float pd = __int_as_float(
          __builtin_amdgcn_ds_bpermute(addr_m1, __float_as_int(d1)));
      pd = (l == 0) ? NEGF : pd;
      const float d0n = fmaxf(x0, pd);
      const float d1n = fmaxf(x1, d0);
      d0 = d0n;
      d1 = d1n;
    }
    // anti-diagonal: A[c] = max(x[c], Aprev[c+1])
    {
      float pa = __int_as_float(
          __builtin_amdgcn_ds_bpermute(addr_p1, __float_as_int(a0)));
      pa = (l == 63) ? NEGF : pa;
      const float a1n = fmaxf(x1, pa);
      const float a0n = fmaxf(x0, a1);
      a0 = a0n;
      a1 = a1n;
    }

    // row inclusive prefix-max over lane totals (DPP, no LDS)
    float y = fmaxf(x0, x1);
    DPP_MAXSTEP(y, 0x111, 0xf);  // row_shr:1
    DPP_MAXSTEP(y, 0x112, 0xf);  // row_shr:2
    DPP_MAXSTEP(y, 0x114, 0xf);  // row_shr:4
    DPP_MAXSTEP(y, 0x118, 0xf);  // row_shr:8
    DPP_MAXSTEP(y, 0x142, 0xa);  // row_bcast15 -> rows 1,3
    DPP_MAXSTEP(y, 0x143, 0xc);  // row_bcast31 -> rows 2,3
    float ex = __int_as_float(
        __builtin_amdgcn_ds_bpermute(addr_m1, __float_as_int(y)));
    ex = (l == 0) ? NEGF : ex;
    const float s0 = fmaxf(ex, x0);  // prefix up to col 2l
    const float s1 = y;              // prefix up to col 2l+1

    const float p0 = (v0 + d0) + (a0 + s0);
    const float p1 = (v1 + d1) + (a1 + s1);
    const int pidx = (row << 6) + slot;
    if (PHASE == 0) {
      // part slot s: lo = even col 2s, hi = odd col 2s+1
      const half2v h = MIR ? __builtin_amdgcn_cvt_pkrtz(p1, p0)
                           : __builtin_amdgcn_cvt_pkrtz(p0, p1);
      part[pidx] = __builtin_bit_cast(unsigned, h);
    } else {
      const half2v h = __builtin_bit_cast(half2v, part[pidx]);
      const float q0 = (float)(MIR ? h.y : h.x);
      const float q1 = (float)(MIR ? h.x : h.y);
      const float o0 = (p0 + q0) * 0.125f;
      const float o1 = (p1 + q1) * 0.125f;
      const float2 ov = MIR ? make_float2(o1, o0) : make_float2(o0, o1);
      *(float2*)(oim + (row << 7) + off) = ov;
    }
  }
}

__global__ __launch_bounds__(128) void pool255_sweep(
    const float* __restrict__ x, float* __restrict__ out) {
  __shared__ unsigned part[NPIX / 2];  // fp16x2, 32 KB -> 5 blocks/CU
  const int img = blockIdx.x;
  const float* __restrict__ xim = x + (size_t)img * NPIX;
  float* __restrict__ oim = out + (size_t)img * NPIX;
  const int l = threadIdx.x & 63;
  const bool mir = threadIdx.x >= 64;
  const int addr_m1 = ((l - 1) & 63) * 4;  // wraps; lane0 fixed by cndmask
  const int addr_p1 = ((l + 1) & 63) * 4;  // wraps; lane63 fixed by cndmask

  float v0 = NEGF, v1 = NEGF, d0 = NEGF, d1 = NEGF, a0 = NEGF, a1 = NEGF;

  if (!mir)
    sweep<false, 0>(xim, oim, part, l, addr_m1, addr_p1, v0, v1, d0, d1, a0, a1);
  else
    sweep<true, 0>(xim, oim, part, l, addr_m1, addr_p1, v0, v1, d0, d1, a0, a1);
  __syncthreads();
  if (!mir)
    sweep<false, 1>(xim, oim, part, l, addr_m1, addr_p1, v0, v1, d0, d1, a0, a1);
  else
    sweep<true, 1>(xim, oim, part, l, addr_m1, addr_p1, v0, v1, d0, d1, a0, a1);
}

extern "C" void kernel_launch(void* const* d_in, const int* in_sizes, int n_in,
                              void* d_out, int out_size, void* d_ws,
                              size_t ws_size, hipStream_t stream) {
  const float* x = (const float*)d_in[0];
  float* out = (float*)d_out;
  const int n_img = in_sizes[0] / NPIX;  // 8*256 = 2048
  pool255_sweep<<<n_img, 128, 0, stream>>>(x, out);
}

// Round 5
// 75.080 us; speedup vs baseline: 3.3061x; 1.1814x over previous
//
#include <hip/hip_runtime.h>

// Pool255: out = (1/8) * sum of 8 directional cumulative-max pools.
// x: [8,256,128,128] fp32. One block (2 waves) per image.
//
// Wave0 sweeps rows top-down computing dirs {(-1,0),(-1,-1),(-1,+1),(0,-1)};
// wave1 sweeps bottom-up in a COLUMN-MIRRORED view (lane l <-> col 127-2l),
// which turns its 4 dirs {(1,0),(1,1),(1,-1),(0,1)} into the SAME recurrences.
// Lane l owns 2 adjacent (view-)columns {2l,2l+1}: vertical = register max,
// diag/anti = 1 ds_bpermute each, row prefix-max = 6-step DPP scan + 1
// bpermute. Phase 0 (64 rows) writes fp16x2 partials to LDS; one barrier;
// phase 1 combines with the other wave's partial and stores out.
//
// R5: depth-4 explicit global prefetch pipeline (G[4], static indexing via
// tb+=4 outer + full-unroll inner). t is continuous across phases, so the
// phase-0 tail prefetches rows 64..67 (phase-1's first rows) before the
// barrier. Phase-1 LDS partial read has a 1-deep prefetch.

#define NPIX 16384
#define NEGF (-3.402823466e38f)

typedef __fp16 half2v __attribute__((ext_vector_type(2)));

// y = max(y, dpp_move(y)) ; masked lanes keep old=y (no-op)
#define DPP_MAXSTEP(y, ctrl, rmask)                                          \
  y = fmaxf(y, __int_as_float(__builtin_amdgcn_update_dpp(                   \
                 __float_as_int(y), __float_as_int(y), ctrl, rmask, 0xf,     \
                 false)))

template <bool MIR>
__device__ __forceinline__ void run(const float* __restrict__ xim,
                                    float* __restrict__ oim,
                                    unsigned* __restrict__ part, const int l,
                                    const int addr_m1, const int addr_p1) {
  const int off = MIR ? (63 - l) * 2 : l * 2;  // float index of the col pair
  const int slot = MIR ? (63 - l) : l;         // u32 slot in a part row

  float v0 = NEGF, v1 = NEGF, d0 = NEGF, d1 = NEGF, a0 = NEGF, a1 = NEGF;

  // depth-4 load pipeline
  float2 G[4];
#pragma unroll
  for (int k = 0; k < 4; ++k) {
    const int row = MIR ? 127 - k : k;
    G[k] = *(const float2*)(xim + (row << 7) + off);
  }

  // ---- phase 0: t = 0..63, write partial ----
  for (int tb = 0; tb < 64; tb += 4) {
#pragma unroll
    for (int k = 0; k < 4; ++k) {
      const int t = tb + k;
      const float2 xv = G[k];
      const int pr = t + 4;  // 4..67: valid, tail pre-issues phase-1 rows
      const int prow = MIR ? 127 - pr : pr;
      G[k] = *(const float2*)(xim + (prow << 7) + off);

      const float x0 = MIR ? xv.y : xv.x;
      const float x1 = MIR ? xv.x : xv.y;

      v0 = fmaxf(v0, x0);
      v1 = fmaxf(v1, x1);

      float pd = __int_as_float(
          __builtin_amdgcn_ds_bpermute(addr_m1, __float_as_int(d1)));
      pd = (l == 0) ? NEGF : pd;
      const float nd0 = fmaxf(x0, pd);
      const float nd1 = fmaxf(x1, d0);
      d0 = nd0; d1 = nd1;

      float pa = __int_as_float(
          __builtin_amdgcn_ds_bpermute(addr_p1, __float_as_int(a0)));
      pa = (l == 63) ? NEGF : pa;
      const float na1 = fmaxf(x1, pa);
      const float na0 = fmaxf(x0, a1);
      a0 = na0; a1 = na1;

      float y = fmaxf(x0, x1);
      DPP_MAXSTEP(y, 0x111, 0xf);  // row_shr:1
      DPP_MAXSTEP(y, 0x112, 0xf);  // row_shr:2
      DPP_MAXSTEP(y, 0x114, 0xf);  // row_shr:4
      DPP_MAXSTEP(y, 0x118, 0xf);  // row_shr:8
      DPP_MAXSTEP(y, 0x142, 0xa);  // row_bcast15 -> rows 1,3
      DPP_MAXSTEP(y, 0x143, 0xc);  // row_bcast31 -> rows 2,3
      float ex = __int_as_float(
          __builtin_amdgcn_ds_bpermute(addr_m1, __float_as_int(y)));
      ex = (l == 0) ? NEGF : ex;
      const float s0 = fmaxf(ex, x0);

      const float p0 = (v0 + d0) + (a0 + s0);
      const float p1 = (v1 + d1) + (a1 + y);

      const int row = MIR ? 127 - t : t;
      const half2v h = MIR ? __builtin_amdgcn_cvt_pkrtz(p1, p0)
                           : __builtin_amdgcn_cvt_pkrtz(p0, p1);
      part[(row << 6) + slot] = __builtin_bit_cast(unsigned, h);
    }
  }

  __syncthreads();

  // ---- phase 1: t = 64..127, combine + store ----
  {
    const int row64 = MIR ? 63 : 64;
    unsigned pb = part[(row64 << 6) + slot];
    for (int tb = 64; tb < 128; tb += 4) {
#pragma unroll
      for (int k = 0; k < 4; ++k) {
        const int t = tb + k;
        const float2 xv = G[k];
        const int pr = (t + 4 < 128) ? t + 4 : 127;  // clamp (uniform)
        const int prow = MIR ? 127 - pr : pr;
        G[k] = *(const float2*)(xim + (prow << 7) + off);

        const unsigned q = pb;
        const int tn = (t + 1 < 128) ? t + 1 : 127;
        const int nrow = MIR ? 127 - tn : tn;
        pb = part[(nrow << 6) + slot];

        const float x0 = MIR ? xv.y : xv.x;
        const float x1 = MIR ? xv.x : xv.y;

        v0 = fmaxf(v0, x0);
        v1 = fmaxf(v1, x1);

        float pd = __int_as_float(
            __builtin_amdgcn_ds_bpermute(addr_m1, __float_as_int(d1)));
        pd = (l == 0) ? NEGF : pd;
        const float nd0 = fmaxf(x0, pd);
        const float nd1 = fmaxf(x1, d0);
        d0 = nd0; d1 = nd1;

        float pa = __int_as_float(
            __builtin_amdgcn_ds_bpermute(addr_p1, __float_as_int(a0)));
        pa = (l == 63) ? NEGF : pa;
        const float na1 = fmaxf(x1, pa);
        const float na0 = fmaxf(x0, a1);
        a0 = na0; a1 = na1;

        float y = fmaxf(x0, x1);
        DPP_MAXSTEP(y, 0x111, 0xf);
        DPP_MAXSTEP(y, 0x112, 0xf);
        DPP_MAXSTEP(y, 0x114, 0xf);
        DPP_MAXSTEP(y, 0x118, 0xf);
        DPP_MAXSTEP(y, 0x142, 0xa);
        DPP_MAXSTEP(y, 0x143, 0xc);
        float ex = __int_as_float(
            __builtin_amdgcn_ds_bpermute(addr_m1, __float_as_int(y)));
        ex = (l == 0) ? NEGF : ex;
        const float s0 = fmaxf(ex, x0);

        const float p0 = (v0 + d0) + (a0 + s0);
        const float p1 = (v1 + d1) + (a1 + y);

        const half2v hq = __builtin_bit_cast(half2v, q);
        const float q0 = (float)(MIR ? hq.y : hq.x);
        const float q1 = (float)(MIR ? hq.x : hq.y);
        const float o0 = (p0 + q0) * 0.125f;
        const float o1 = (p1 + q1) * 0.125f;

        const int row = MIR ? 127 - t : t;
        const float2 ov = MIR ? make_float2(o1, o0) : make_float2(o0, o1);
        *(float2*)(oim + (row << 7) + off) = ov;
      }
    }
  }
}

__global__ __launch_bounds__(128) void pool255_sweep(
    const float* __restrict__ x, float* __restrict__ out) {
  __shared__ unsigned part[NPIX / 2];  // fp16x2, 32 KB -> 5 blocks/CU
  const int img = blockIdx.x;
  const float* __restrict__ xim = x + (size_t)img * NPIX;
  float* __restrict__ oim = out + (size_t)img * NPIX;
  const int l = threadIdx.x & 63;
  const int addr_m1 = ((l - 1) & 63) * 4;  // wraps; lane0 fixed by cndmask
  const int addr_p1 = ((l + 1) & 63) * 4;  // wraps; lane63 fixed by cndmask

  if (threadIdx.x < 64)
    run<false>(xim, oim, part, l, addr_m1, addr_p1);
  else
    run<true>(xim, oim, part, l, addr_m1, addr_p1);
}

extern "C" void kernel_launch(void* const* d_in, const int* in_sizes, int n_in,
                              void* d_out, int out_size, void* d_ws,
                              size_t ws_size, hipStream_t stream) {
  const float* x = (const float*)d_in[0];
  float* out = (float*)d_out;
  const int n_img = in_sizes[0] / NPIX;  // 8*256 = 2048
  pool255_sweep<<<n_img, 128, 0, stream>>>(x, out);
}